// Round 7
// baseline (239.385 us; speedup 1.0000x reference)
//
#include <hip/hip_runtime.h>
#include <cstdint>
#include <cstddef>

// v: (B=16, L=16384, D=128) fp32.
// out[b, 2j+e, d] = (e==0 ? min : max)(v[b, p, d], v[b, p+1, d]),
//   p = (2j - s_d) mod L,  s_d = (d==0 ? 0 : 2d-2)  (always even).
#define L_DIM 16384
#define D_DIM 128
#define B_DIM 16

#define DG 32               // columns per block (128B segments)
#define NRING 512           // LDS ring rows (64 KB) -> 2 blocks/CU
#define RMASK (NRING - 1)
#define BATCH 128           // rows per load batch (16 KB)
#define CHUNK 2048          // output rows per block
#define NB_OUT (CHUNK / BATCH)   // 16 compute batches
// input batches = NB_OUT + 1 (ring covers out rows + 192-row shifted span)

typedef const __attribute__((address_space(1))) uint32_t GBuf;
typedef __attribute__((address_space(3))) uint32_t LBuf;

__global__ __launch_bounds__(512, 4) void butterfly_ring_kernel(
    const float* __restrict__ v, float* __restrict__ out) {
  __shared__ float lds[NRING * DG];  // 64 KB ring, linear [slot][32]

  const int chunk = blockIdx.x;  // 0..7 ; linear id % 8 == chunk -> one row
  const int g     = blockIdx.y;  // 0..3   range per XCD (L2 locality)
  const int b     = blockIdx.z;

  const int R0  = chunk * CHUNK;
  const int d0  = g * DG;
  const int IN0 = R0 - 64 * (g + 1);  // first (unwrapped) staged input row

  const int t    = threadIdx.x;
  const int lane = t & 63;
  const int wave = t >> 6;  // 0..7

  const float* vb = v   + (size_t)b * (L_DIM * D_DIM);
  float*       ob = out + (size_t)b * (L_DIM * D_DIM);

  // Load mapping: one instr = 8 rows x 128B = 1KB; lane covers
  // row lane/8, float4-col lane%8. LDS dest linear (wave-uniform base).
  const int lrow  = lane >> 3;
  const int lcol4 = lane & 7;

#define ISSUE_BATCH(kk)                                                      \
  {                                                                          \
    _Pragma("unroll")                                                        \
    for (int p = 0; p < 2; ++p) {                                            \
      const int sub  = wave * 2 + p;               /* 0..15 */               \
      const int rb   = sub * 8 + lrow;             /* row within batch */    \
      const int grow = (IN0 + (kk)*BATCH + rb) & (L_DIM - 1);                \
      const float* gp = vb + (size_t)grow * D_DIM + d0 + lcol4 * 4;          \
      float* lp = &lds[((((kk)*BATCH) & RMASK) + sub * 8) * DG];             \
      __builtin_amdgcn_global_load_lds((GBuf*)gp, (LBuf*)lp, 16, 0, 0);      \
    }                                                                        \
  }

  // Per-thread compute constants.
  const int c   = t & 31;        // column within group
  const int jr2 = (t >> 5) * 2;  // 2 * pair-subgroup (0,2,..,30)
  const int d   = d0 + c;
  const int boff = (d == 0) ? 64 : (66 - 2 * c);  // 64(g+1) - s_d, in [4,66]

  // Prologue: 2 batches in flight.
  ISSUE_BATCH(0);
  ISSUE_BATCH(1);

#pragma unroll 4
  for (int k = 0; k < NB_OUT; ++k) {
    if (k < NB_OUT - 1) ISSUE_BATCH(k + 2);
    // Counted vmcnt: retire prev-batch loads; keep new loads + up to 8
    // stores (from compute k-1) in flight. Never vmcnt(0) mid-loop.
    if (k == 0) {
      asm volatile("s_waitcnt vmcnt(2)" ::: "memory");   // L0,L1 done
    } else if (k < NB_OUT - 1) {
      asm volatile("s_waitcnt vmcnt(10)" ::: "memory");  // 8 st + 2 ld fly
    } else {
      asm volatile("s_waitcnt vmcnt(8)" ::: "memory");   // 8 st fly
    }
    __builtin_amdgcn_s_barrier();

    const int kb  = k * BATCH;
    const int R0k = R0 + kb;
#pragma unroll
    for (int q = 0; q < 4; ++q) {
      const int m2  = 32 * q + jr2;          // even out-row offset in batch
      const int rel = kb + m2 + boff;        // unwrapped input-row - IN0
      const int s0  = rel & RMASK;
      const int s1  = (rel + 1) & RMASK;
      const float a0 = lds[s0 * DG + c];     // bank == c: 2-way, free
      const float a1 = lds[s1 * DG + c];
      const float lo = fminf(a0, a1);
      const float hi = fmaxf(a0, a1);
      float* op = ob + (size_t)(R0k + m2) * D_DIM + d;
      op[0]     = lo;                        // 32 lanes = one 128B line
      op[D_DIM] = hi;
    }
  }
#undef ISSUE_BATCH
}

extern "C" void kernel_launch(void* const* d_in, const int* in_sizes, int n_in,
                              void* d_out, int out_size, void* d_ws, size_t ws_size,
                              hipStream_t stream) {
  const float* v = (const float*)d_in[0];
  float* out = (float*)d_out;
  dim3 grid(L_DIM / CHUNK, D_DIM / DG, B_DIM);  // (8, 4, 16) = 512 blocks
  dim3 block(512);
  butterfly_ring_kernel<<<grid, block, 0, stream>>>(v, out);
}

// Round 8
// 229.384 us; speedup vs baseline: 1.0436x; 1.0436x over previous
//
#include <hip/hip_runtime.h>
#include <cstdint>
#include <cstddef>

// v: (B=16, L=16384, D=128) fp32.
// out[b, 2j+e, d] = (e==0 ? min : max)(v[b, p, d], v[b, p+1, d]),
//   p = (2j - s_d) mod L,  s_d = (d==0 ? 0 : 2d-2)  (always even).
//
// A/B experiment vs rounds 1-7: stage global->LDS via REGISTER loads
// (global_load_dwordx4 -> VGPR -> ds_write_b128) instead of
// global_load_lds, testing the shallow-LDS-DMA-queue theory for the
// ~2.4 TB/s read ceiling. Independent blocks, stores never waited on.
#define L_DIM 16384
#define D_DIM 128
#define B_DIM 16

#define TR 512            // output rows per block
#define DG 32             // columns per block (128B segments)
#define HALO 64           // shift span within a col group (62) rounded up
#define ROWS (TR + HALO)  // 576 staged input rows
#define NSWEEP (ROWS / 64)  // 9 register-staged sweeps (64 rows each)

__global__ __launch_bounds__(512, 2) void butterfly_reg_kernel(
    const float* __restrict__ v, float* __restrict__ out) {
  __shared__ float lds[ROWS * DG];  // 72 KB -> 2 blocks/CU

  const int rtile = blockIdx.x;  // 0..31
  const int g     = blockIdx.y;  // 0..3
  const int b     = blockIdx.z;  // 0..15
  const int r0    = rtile * TR;
  const int d0    = g * DG;
  const int smax  = 64 * g + 60;   // max shift in this column group
  const int rin0  = r0 - smax;     // first staged input row (may be < 0)

  const int t = threadIdx.x;

  const float* vb = v   + (size_t)b * (L_DIM * D_DIM);
  float*       ob = out + (size_t)b * (L_DIM * D_DIM);

  // ---- Stage: 9 x float4 per thread, issued back-to-back, then ds_write.
  // 8 threads per row (8 x 16B = 128B), 64 rows per sweep.
  const int srow  = t >> 3;          // 0..63 row within sweep
  const int scol4 = t & 7;           // 0..7  float4-column
  float4 stg[NSWEEP];
#pragma unroll
  for (int s = 0; s < NSWEEP; ++s) {
    const int rt   = s * 64 + srow;                  // row in tile
    const int grow = (rin0 + rt) & (L_DIM - 1);
    stg[s] = *reinterpret_cast<const float4*>(
        vb + (size_t)grow * D_DIM + d0 + scol4 * 4);
  }
#pragma unroll
  for (int s = 0; s < NSWEEP; ++s) {
    const int rt = s * 64 + srow;
    *reinterpret_cast<float4*>(&lds[rt * DG + scol4 * 4]) = stg[s];
  }
  __syncthreads();

  // ---- Compute: diagonal pair gather from LDS, min/max, coalesced store.
  const int c  = t & 31;   // column within group; bank==c -> 2-way, free
  const int sg = t >> 5;   // 0..15 pair-row subgroup
  const int d  = d0 + c;
  const int s_d  = (d == 0) ? 0 : (2 * d - 2);
  const int boff = smax - s_d;  // 0..62; tile row = 2*pr + boff < ROWS

#pragma unroll
  for (int kk = 0; kk < TR / 32; ++kk) {  // 16 iterations
    const int pr = kk * 16 + sg;          // pair index 0..255
    const int lr = 2 * pr + boff;
    const float a0 = lds[lr * DG + c];
    const float a1 = lds[(lr + 1) * DG + c];
    const float lo = fminf(a0, a1);
    const float hi = fmaxf(a0, a1);
    float* op = ob + (size_t)(r0 + 2 * pr) * D_DIM + d;
    op[0]     = lo;   // each half-wave covers one 128B segment
    op[D_DIM] = hi;
  }
}

extern "C" void kernel_launch(void* const* d_in, const int* in_sizes, int n_in,
                              void* d_out, int out_size, void* d_ws, size_t ws_size,
                              hipStream_t stream) {
  const float* v = (const float*)d_in[0];
  float* out = (float*)d_out;
  dim3 grid(L_DIM / TR, D_DIM / DG, B_DIM);  // (32, 4, 16) = 2048 blocks
  dim3 block(512);
  butterfly_reg_kernel<<<grid, block, 0, stream>>>(v, out);
}